// Round 5
// baseline (147.743 us; speedup 1.0000x reference)
//
#include <hip/hip_runtime.h>
#include <stdint.h>

using i32x4 = __attribute__((ext_vector_type(4))) int;
using i32x8 = __attribute__((ext_vector_type(8))) int;
using f32x4 = __attribute__((ext_vector_type(4))) float;

#define M_ROWS 8192
#define N_COLS 4096
#define K_DIM  4096
#define KB_ROW 2048          // bytes per packed fp4 row (2 elems/byte)
#define BM 128
#define BN 128
#define TKB 128              // K-bytes per tile (= 256 fp4 elements)
#define NT (KB_ROW / TKB)    // 16 K-tiles
#define SC1 0x7F7F7F7F       // E8M0 = 127 -> scale 1.0, all bytes

// ------------- Pass 1: binarize f32 -> fp4 e2m1 {+1,-1} nibbles -------------
// element 8i+j of a row -> bits [4j+3:4j] of out dword i. +1=0x2, -1=0xA.
// x and w outputs are contiguous in d_ws (xa then wb), so one fused
// grid-stride kernel covers both.
#define XDW   ((size_t)M_ROWS * K_DIM / 8)                  // 4,194,304
#define TOTDW (((size_t)(M_ROWS + N_COLS)) * K_DIM / 8)     // 6,291,456
__global__ __launch_bounds__(256) void binarize_fp4_fused(
    const float4* __restrict__ x, const float4* __restrict__ w,
    unsigned* __restrict__ out) {
  size_t idx = (size_t)blockIdx.x * blockDim.x + threadIdx.x;
  size_t stride = (size_t)gridDim.x * blockDim.x;
  for (size_t i = idx; i < TOTDW; i += stride) {
    const float4* src = (i < XDW) ? x : w;
    size_t j = (i < XDW) ? i : (i - XDW);
    float4 a = src[2 * j], b = src[2 * j + 1];
    unsigned neg =
        ((a.x > 0.f ? 0u : 1u) << 3)  | ((a.y > 0.f ? 0u : 1u) << 7)  |
        ((a.z > 0.f ? 0u : 1u) << 11) | ((a.w > 0.f ? 0u : 1u) << 15) |
        ((b.x > 0.f ? 0u : 1u) << 19) | ((b.y > 0.f ? 0u : 1u) << 23) |
        ((b.z > 0.f ? 0u : 1u) << 27) | ((b.w > 0.f ? 0u : 1u) << 31);
    out[i] = 0x22222222u | neg;
  }
}

// ---------------- global -> LDS direct (16B per lane) ----------------
#define GLOAD(gsrc, ldst)                                                    \
  __builtin_amdgcn_global_load_lds(                                          \
      (const __attribute__((address_space(1))) void*)(gsrc),                 \
      (__attribute__((address_space(3))) void*)(ldst), 16, 0, 0)

// -------- Pass 2: fp4 MFMA GEMM, 128^2 tile, 2 blocks/CU, 4-phase --------
// LDS per operand: [2 buf][2 khalf][128 rows][64 B] = 32 KB; total 64 KB
// -> 2 blocks/CU so one block's MFMA covers the other's barrier drains.
// Slot-XOR swizzle (slot ^ ((row>>1)&3)) applied on the global source
// (gload_lds writes linearly), undone on the ds_read side.
// Stage unit = 128 rows x one khalf = 8 KB = 1 gload/thread.
// Counted vmcnt(2) at phases 2 and 4: in-flight 2-4 gloads, never 0.

#define STG_A(NB, KBo, KH)                                                   \
  GLOAD(aS0 + (KBo) + (KH) * 64, As + (NB) + (KH) * 8192 + dstW)

#define STG_B(NB, KBo, KH)                                                   \
  GLOAD(bS0 + (KBo) + (KH) * 64, Bs + (NB) + (KH) * 8192 + dstW)

#define DO_PHASE(BUFOFF, KHOFF, MH, BLOAD, STAGE_STMT, PRE_CLOSE)            \
  {                                                                          \
    STAGE_STMT                                                               \
    if (BLOAD) {                                                             \
      _Pragma("unroll")                                                      \
      for (int nf = 0; nf < 2; ++nf)                                         \
        *(i32x4*)&bf8[nf] =                                                  \
            *(const i32x4*)(Bs + (BUFOFF) + (KHOFF) + bRdOff + nf * 1024);   \
    }                                                                        \
    _Pragma("unroll")                                                        \
    for (int mf = 0; mf < 2; ++mf)                                           \
      *(i32x4*)&af8[mf] = *(const i32x4*)(As + (BUFOFF) + (KHOFF) +          \
                                          aRdOff + (MH) * 2048 + mf * 1024); \
    __builtin_amdgcn_s_barrier();                                            \
    __builtin_amdgcn_s_setprio(1);                                           \
    _Pragma("unroll")                                                        \
    for (int mf = 0; mf < 2; ++mf) {                                         \
      _Pragma("unroll")                                                      \
      for (int nf = 0; nf < 2; ++nf)                                         \
        acc[(MH) * 2 + mf][nf] =                                             \
            __builtin_amdgcn_mfma_scale_f32_16x16x128_f8f6f4(                \
                af8[mf], bf8[nf], acc[(MH) * 2 + mf][nf], 4, 4, 0, SC1, 0,   \
                SC1);                                                        \
    }                                                                        \
    __builtin_amdgcn_s_setprio(0);                                           \
    PRE_CLOSE                                                                \
    __builtin_amdgcn_s_barrier();                                            \
  }

#define TILE_NORMAL(BUFOFF, NBUFOFF, KBo)                                    \
  DO_PHASE(BUFOFF, 0, 0, true, STG_A(NBUFOFF, KBo, 0);, )                    \
  DO_PHASE(BUFOFF, 0, 1, false, STG_B(NBUFOFF, KBo, 0);,                     \
           asm volatile("s_waitcnt vmcnt(2)" ::: "memory");)                 \
  DO_PHASE(BUFOFF, 8192, 0, true, STG_A(NBUFOFF, KBo, 1);, )                 \
  DO_PHASE(BUFOFF, 8192, 1, false, STG_B(NBUFOFF, KBo, 1);,                  \
           asm volatile("s_waitcnt vmcnt(2)" ::: "memory");)

#define TILE_LAST(BUFOFF)                                                    \
  DO_PHASE(BUFOFF, 0, 0, true, , )                                           \
  DO_PHASE(BUFOFF, 0, 1, false, ,                                            \
           asm volatile("s_waitcnt vmcnt(0)" ::: "memory");)                 \
  DO_PHASE(BUFOFF, 8192, 0, true, , )                                        \
  DO_PHASE(BUFOFF, 8192, 1, false, , )

__global__ __launch_bounds__(512, 4) void bgemm_fp4_128(
    const unsigned char* __restrict__ xa, const unsigned char* __restrict__ wb,
    const float* __restrict__ bias, float* __restrict__ y) {
  __shared__ __align__(16) unsigned char As[32768];
  __shared__ __align__(16) unsigned char Bs[32768];

  const int tid  = threadIdx.x;
  const int lane = tid & 63;
  const int w8   = tid >> 6;   // wave 0..7
  const int wr   = w8 >> 2;    // wave M-row 0..1 (64 rows each)
  const int wc   = w8 & 3;     // wave N-col 0..3 (32 cols each)

  // bijective XCD swizzle (2048 blocks, 2048 % 8 == 0); within an XCD
  // chunk consecutive sw walk bx fast -> shared A-panel stays in L2
  const int id = blockIdx.x;
  const int sw = ((id & 7) << 8) | (id >> 3);
  const int by = sw >> 5;      // 0..63 M-block
  const int bx = sw & 31;      // 0..31 N-block
  const int m0 = by * BM;
  const int n0 = bx * BN;

  // ---- staging geometry: thread covers LDS row tid>>2, slot tid&3
  const int r0  = tid >> 2;
  const int gsl = (((tid & 3) ^ ((tid >> 3) & 3)) << 4);  // inverse swizzle
  const unsigned char* aS0 = xa + (size_t)(m0 + r0) * KB_ROW + gsl;
  const unsigned char* bS0 = wb + (size_t)(n0 + r0) * KB_ROW + gsl;
  const int dstW = w8 * 1024;  // wave-uniform LDS dest (HW adds lane*16)

  // ---- fragment-read geometry (16x16x128 fp4: lane lr = row, kq = 16B grp)
  const int lr  = lane & 15;
  const int kq  = lane >> 4;
  const int rsw = (kq ^ ((lr >> 1) & 3)) << 4;   // swizzled read slot
  const int aRdOff = (wr * 64 + lr) * 64 + rsw;  // + MH*2048 + mf*1024
  const int bRdOff = (wc * 32 + lr) * 64 + rsw;  // + nf*1024

  f32x4 acc[4][2];
#pragma unroll
  for (int i = 0; i < 4; ++i)
#pragma unroll
    for (int j = 0; j < 2; ++j) acc[i][j] = (f32x4){0.f, 0.f, 0.f, 0.f};

  // fp4 data lives in the LOW 4 regs of the 8-reg operand; high half stays 0
  i32x8 af8[2], bf8[2];
#pragma unroll
  for (int i = 0; i < 2; ++i) {
    af8[i] = (i32x8){0, 0, 0, 0, 0, 0, 0, 0};
    bf8[i] = (i32x8){0, 0, 0, 0, 0, 0, 0, 0};
  }

  // prologue: stage tile 0 (A0,B0,A1,B1 = 4 gloads); first 2 must land
  STG_A(0, 0, 0);
  STG_B(0, 0, 0);
  STG_A(0, 0, 1);
  STG_B(0, 0, 1);
  asm volatile("s_waitcnt vmcnt(2)" ::: "memory");
  __builtin_amdgcn_s_barrier();

#pragma unroll 1
  for (int tp = 0; tp < 7; ++tp) {
    const int kb1 = tp * 256 + 128;   // tile 2tp+1
    const int kb2 = tp * 256 + 256;   // tile 2tp+2
    TILE_NORMAL(0, 16384, kb1)
    TILE_NORMAL(16384, 0, kb2)
  }
  TILE_NORMAL(0, 16384, 1920)   // tile 14, stages tile 15
  TILE_LAST(16384)              // tile 15

  // epilogue: C/D map col = lane&15, row = kq*4 + j (shape-determined)
  float bv[2];
#pragma unroll
  for (int nf = 0; nf < 2; ++nf) bv[nf] = bias[n0 + wc * 32 + nf * 16 + lr];
#pragma unroll
  for (int fr = 0; fr < 4; ++fr) {
#pragma unroll
    for (int j = 0; j < 4; ++j) {
      const int gr = m0 + wr * 64 + fr * 16 + kq * 4 + j;
      float* orow = y + (size_t)gr * N_COLS + n0 + wc * 32 + lr;
#pragma unroll
      for (int nf = 0; nf < 2; ++nf)
        orow[nf * 16] = acc[fr][nf][j] + bv[nf];
    }
  }
}

// =========================================================================
extern "C" void kernel_launch(void* const* d_in, const int* in_sizes, int n_in,
                              void* d_out, int out_size, void* d_ws, size_t ws_size,
                              hipStream_t stream) {
  const float* x    = (const float*)d_in[0];
  const float* wgt  = (const float*)d_in[1];
  const float* bias = (const float*)d_in[2];
  float* y = (float*)d_out;

  unsigned char* xa = (unsigned char*)d_ws;             // 8192*2048 = 16 MB
  unsigned char* wb = xa + (size_t)M_ROWS * KB_ROW;     // 4096*2048 =  8 MB

  binarize_fp4_fused<<<2048, 256, 0, stream>>>(
      (const float4*)x, (const float4*)wgt, (unsigned*)xa);

  dim3 grid((M_ROWS / BM) * (N_COLS / BN));  // 2048
  bgemm_fp4_128<<<grid, 512, 0, stream>>>(xa, wb, bias, y);
}

// Round 6
// 131.495 us; speedup vs baseline: 1.1236x; 1.1236x over previous
//
#include <hip/hip_runtime.h>
#include <stdint.h>

using i32x4 = __attribute__((ext_vector_type(4))) int;
using i32x8 = __attribute__((ext_vector_type(8))) int;
using f32x4 = __attribute__((ext_vector_type(4))) float;

#define M_ROWS 8192
#define N_COLS 4096
#define K_DIM  4096
#define KB_ROW 2048          // bytes per packed fp4 row (2 elems/byte)
#define BM 256
#define BN 256
#define TKB 128              // K-bytes per tile (= 256 fp4 elements)
#define NT (KB_ROW / TKB)    // 16 K-tiles
#define SC1 0x7F7F7F7F       // E8M0 = 127 -> scale 1.0, all bytes

// ------------- Pass 1: binarize f32 -> fp4 e2m1 {+1,-1} nibbles -------------
// element 8i+j of a row -> bits [4j+3:4j] of out dword i. +1=0x2, -1=0xA.
// Each thread emits 2 out-dwords per iter (4 float4 loads in flight).
#define XDW   ((size_t)M_ROWS * K_DIM / 8)                  // 4,194,304
#define TOTDW (((size_t)(M_ROWS + N_COLS)) * K_DIM / 8)     // 6,291,456

__device__ __forceinline__ unsigned pack8(float4 a, float4 b) {
  unsigned neg =
      ((a.x > 0.f ? 0u : 1u) << 3)  | ((a.y > 0.f ? 0u : 1u) << 7)  |
      ((a.z > 0.f ? 0u : 1u) << 11) | ((a.w > 0.f ? 0u : 1u) << 15) |
      ((b.x > 0.f ? 0u : 1u) << 19) | ((b.y > 0.f ? 0u : 1u) << 23) |
      ((b.z > 0.f ? 0u : 1u) << 27) | ((b.w > 0.f ? 0u : 1u) << 31);
  return 0x22222222u | neg;
}

__global__ __launch_bounds__(256) void binarize_fp4_fused(
    const float4* __restrict__ x, const float4* __restrict__ w,
    unsigned* __restrict__ out) {
  size_t u = (size_t)blockIdx.x * blockDim.x + threadIdx.x;
  size_t stride = (size_t)gridDim.x * blockDim.x;
  for (; u < TOTDW / 2; u += stride) {
    size_t d = u * 2;                       // first of 2 out dwords
    const float4* s;
    size_t j;
    if (d < XDW) { s = x; j = d * 2; }
    else         { s = w; j = (d - XDW) * 2; }
    float4 f0 = s[j], f1 = s[j + 1], f2 = s[j + 2], f3 = s[j + 3];
    out[d]     = pack8(f0, f1);
    out[d + 1] = pack8(f2, f3);
  }
}

// ---------------- global -> LDS direct (16B per lane) ----------------
#define GLOAD(gsrc, ldst)                                                    \
  __builtin_amdgcn_global_load_lds(                                          \
      (const __attribute__((address_space(1))) void*)(gsrc),                 \
      (__attribute__((address_space(3))) void*)(ldst), 16, 0, 0)

// -------- Pass 2: fp4 MFMA GEMM, 256^2 tile, 2 barriers per K-tile --------
// LDS per operand: [2 buf][2 khalf][256 rows][64 B] = 64 KB; slot-XOR
// swizzle (slot ^ ((row>>1)&3)) applied on the global source (gload_lds
// writes linearly), undone on ds_read -> conflict-free b128 reads.
// Per K-tile: 2 phases (one per 64B khalf), each {stage 4 gloads of next
// tile's matching khalf; 12 ds_read_b128; 32 MFMA; vmcnt(4); barrier}.
// Per-wave vmcnt induction: at each phase close, vmcnt(4) retires the
// previous stage batch; barrier joins all waves -> staged khalf visible
// one full tile before it is read. In-flight gloads oscillate 4<->8,
// never drained to 0 in the main loop.

#define STG_A(NB, KBo, KH)                                                   \
  GLOAD(aS0 + (KBo) + (KH) * 64, As + (NB) + (KH) * 16384 + dstW);           \
  GLOAD(aS1 + (KBo) + (KH) * 64, As + (NB) + (KH) * 16384 + 8192 + dstW)

#define STG_B(NB, KBo, KH)                                                   \
  GLOAD(bS0 + (KBo) + (KH) * 64, Bs + (NB) + (KH) * 16384 + dstW);           \
  GLOAD(bS1 + (KBo) + (KH) * 64, Bs + (NB) + (KH) * 16384 + 8192 + dstW)

#define VM4BAR                                                               \
  asm volatile("s_waitcnt vmcnt(4)" ::: "memory");                           \
  __builtin_amdgcn_s_barrier();

#define VM0BAR                                                               \
  asm volatile("s_waitcnt vmcnt(0)" ::: "memory");                           \
  __builtin_amdgcn_s_barrier();

#define DO_PHASE(BUFOFF, KHOFF, STAGE_STMT, CLOSE_STMT)                      \
  {                                                                          \
    STAGE_STMT                                                               \
    _Pragma("unroll")                                                        \
    for (int nf = 0; nf < 4; ++nf)                                           \
      *(i32x4*)&bf8[nf] =                                                    \
          *(const i32x4*)(Bs + (BUFOFF) + (KHOFF) + bRdOff + nf * 1024);     \
    __builtin_amdgcn_s_setprio(1);                                           \
    _Pragma("unroll")                                                        \
    for (int fr = 0; fr < 8; ++fr) {                                         \
      *(i32x4*)&af8[fr & 1] =                                                \
          *(const i32x4*)(As + (BUFOFF) + (KHOFF) + aRdOff + fr * 1024);     \
      _Pragma("unroll")                                                      \
      for (int nf = 0; nf < 4; ++nf)                                         \
        acc[fr][nf] = __builtin_amdgcn_mfma_scale_f32_16x16x128_f8f6f4(      \
            af8[fr & 1], bf8[nf], acc[fr][nf], 4, 4, 0, SC1, 0, SC1);        \
    }                                                                        \
    __builtin_amdgcn_s_setprio(0);                                           \
    CLOSE_STMT                                                               \
  }

#define TILE(BUF, NBUF, KBo)                                                 \
  DO_PHASE(BUF, 0,     STG_A(NBUF, KBo, 0); STG_B(NBUF, KBo, 0);, VM4BAR)    \
  DO_PHASE(BUF, 16384, STG_A(NBUF, KBo, 1); STG_B(NBUF, KBo, 1);, VM4BAR)

#define TILE_LAST(BUF)                                                       \
  DO_PHASE(BUF, 0, , VM0BAR)                                                 \
  DO_PHASE(BUF, 16384, , )

__global__ __launch_bounds__(512, 2) void bgemm_fp4_2bar(
    const unsigned char* __restrict__ xa, const unsigned char* __restrict__ wb,
    const float* __restrict__ bias, float* __restrict__ y) {
  __shared__ __align__(16) unsigned char As[65536];
  __shared__ __align__(16) unsigned char Bs[65536];

  const int tid  = threadIdx.x;
  const int lane = tid & 63;
  const int w8   = tid >> 6;   // wave 0..7
  const int wr   = w8 >> 2;    // wave M-row 0..1 (128 rows each)
  const int wc   = w8 & 3;     // wave N-col 0..3 (64 cols each)

  // bijective XCD swizzle (512 blocks, 512 % 8 == 0)
  const int id = blockIdx.x;
  const int sw = ((id & 7) << 6) | (id >> 3);
  const int by = sw >> 4;      // 0..31 M-block
  const int bx = sw & 15;      // 0..15 N-block
  const int m0 = by * BM;
  const int n0 = bx * BN;

  // ---- staging geometry: thread covers LDS row tid>>2, slot tid&3
  const int r0  = tid >> 2;
  const int gsl = (((tid & 3) ^ ((tid >> 3) & 3)) << 4);  // inverse swizzle
  const unsigned char* aS0 = xa + (size_t)(m0 + r0) * KB_ROW + gsl;
  const unsigned char* aS1 = xa + (size_t)(m0 + 128 + r0) * KB_ROW + gsl;
  const unsigned char* bS0 = wb + (size_t)(n0 + r0) * KB_ROW + gsl;
  const unsigned char* bS1 = wb + (size_t)(n0 + 128 + r0) * KB_ROW + gsl;
  const int dstW = w8 * 1024;  // wave-uniform LDS dest (HW adds lane*16)

  // ---- fragment-read geometry (16x16x128 fp4: lane lr = row, kq = 16B grp)
  const int lr  = lane & 15;
  const int kq  = lane >> 4;
  const int rsw = (kq ^ ((lr >> 1) & 3)) << 4;   // swizzled read slot
  const int aRdOff = (wr * 128 + lr) * 64 + rsw; // + fr*1024
  const int bRdOff = (wc * 64 + lr) * 64 + rsw;  // + nf*1024

  f32x4 acc[8][4];
#pragma unroll
  for (int i = 0; i < 8; ++i)
#pragma unroll
    for (int j = 0; j < 4; ++j) acc[i][j] = (f32x4){0.f, 0.f, 0.f, 0.f};

  // fp4 data lives in the LOW 4 regs of the 8-reg operand; high half stays 0
  i32x8 af8[2], bf8[4];
#pragma unroll
  for (int i = 0; i < 2; ++i) af8[i] = (i32x8){0, 0, 0, 0, 0, 0, 0, 0};
#pragma unroll
  for (int i = 0; i < 4; ++i) bf8[i] = (i32x8){0, 0, 0, 0, 0, 0, 0, 0};

  // prologue: stage tile 0 (kh0 then kh1, 8 gloads); wait kh0 batch
  STG_A(0, 0, 0);
  STG_B(0, 0, 0);
  STG_A(0, 0, 1);
  STG_B(0, 0, 1);
  asm volatile("s_waitcnt vmcnt(4)" ::: "memory");
  __builtin_amdgcn_s_barrier();

#pragma unroll 1
  for (int tp = 0; tp < 7; ++tp) {
    const int kb1 = tp * 256 + 128;   // tile 2tp+1
    const int kb2 = tp * 256 + 256;   // tile 2tp+2
    TILE(0, 32768, kb1)
    TILE(32768, 0, kb2)
  }
  TILE(0, 32768, 1920)   // tile 14, stages tile 15
  TILE_LAST(32768)       // tile 15

  // epilogue: C/D map col = lane&15, row = kq*4 + j (shape-determined)
  float bv[4];
#pragma unroll
  for (int nf = 0; nf < 4; ++nf) bv[nf] = bias[n0 + wc * 64 + nf * 16 + lr];
#pragma unroll
  for (int fr = 0; fr < 8; ++fr) {
#pragma unroll
    for (int j = 0; j < 4; ++j) {
      const int gr = m0 + wr * 128 + fr * 16 + kq * 4 + j;
      float* orow = y + (size_t)gr * N_COLS + n0 + wc * 64 + lr;
#pragma unroll
      for (int nf = 0; nf < 4; ++nf)
        orow[nf * 16] = acc[fr][nf][j] + bv[nf];
    }
  }
}

// =========================================================================
extern "C" void kernel_launch(void* const* d_in, const int* in_sizes, int n_in,
                              void* d_out, int out_size, void* d_ws, size_t ws_size,
                              hipStream_t stream) {
  const float* x    = (const float*)d_in[0];
  const float* wgt  = (const float*)d_in[1];
  const float* bias = (const float*)d_in[2];
  float* y = (float*)d_out;

  unsigned char* xa = (unsigned char*)d_ws;             // 8192*2048 = 16 MB
  unsigned char* wb = xa + (size_t)M_ROWS * KB_ROW;     // 4096*2048 =  8 MB

  binarize_fp4_fused<<<4096, 256, 0, stream>>>(
      (const float4*)x, (const float4*)wgt, (unsigned*)xa);

  bgemm_fp4_2bar<<<512, 512, 0, stream>>>(xa, wb, bias, y);
}

// Round 7
// 130.556 us; speedup vs baseline: 1.1316x; 1.0072x over previous
//
#include <hip/hip_runtime.h>
#include <stdint.h>

using i32x4  = __attribute__((ext_vector_type(4))) int;
using i32x8  = __attribute__((ext_vector_type(8))) int;
using f32x16 = __attribute__((ext_vector_type(16))) float;

#define M_ROWS 8192
#define N_COLS 4096
#define K_DIM  4096
#define KB_ROW 2048          // bytes per packed fp4 row (2 elems/byte)
#define BM 256
#define BN 256
#define SC1 0x7F7F7F7F       // E8M0 = 127 -> scale 1.0, all bytes

// ------------- Pass 1: binarize f32 -> fp4 e2m1 {+1,-1} nibbles -------------
// element 8i+j of a row -> bits [4j+3:4j] of out dword i. +1=0x2, -1=0xA.
// 4 out-dwords (8 float4 loads, 128 B) per thread-iter; uint4 store.
#define XDW   ((size_t)M_ROWS * K_DIM / 8)                  // 4,194,304
#define TOTDW (((size_t)(M_ROWS + N_COLS)) * K_DIM / 8)     // 6,291,456

__device__ __forceinline__ unsigned pack8(float4 a, float4 b) {
  unsigned neg =
      ((a.x > 0.f ? 0u : 1u) << 3)  | ((a.y > 0.f ? 0u : 1u) << 7)  |
      ((a.z > 0.f ? 0u : 1u) << 11) | ((a.w > 0.f ? 0u : 1u) << 15) |
      ((b.x > 0.f ? 0u : 1u) << 19) | ((b.y > 0.f ? 0u : 1u) << 23) |
      ((b.z > 0.f ? 0u : 1u) << 27) | ((b.w > 0.f ? 0u : 1u) << 31);
  return 0x22222222u | neg;
}

__global__ __launch_bounds__(256) void binarize_fp4_fused(
    const float4* __restrict__ x, const float4* __restrict__ w,
    uint4* __restrict__ out) {
  size_t u = (size_t)blockIdx.x * blockDim.x + threadIdx.x;  // quad index
  size_t stride = (size_t)gridDim.x * blockDim.x;
  for (; u < TOTDW / 4; u += stride) {
    size_t d = u * 4;                       // first of 4 out dwords
    const float4* s;
    size_t j;
    if (d < XDW) { s = x; j = d * 2; }      // XDW % 4 == 0: no straddle
    else         { s = w; j = (d - XDW) * 2; }
    float4 f0 = s[j], f1 = s[j + 1], f2 = s[j + 2], f3 = s[j + 3];
    float4 f4 = s[j + 4], f5 = s[j + 5], f6 = s[j + 6], f7 = s[j + 7];
    uint4 o;
    o.x = pack8(f0, f1);
    o.y = pack8(f2, f3);
    o.z = pack8(f4, f5);
    o.w = pack8(f6, f7);
    out[u] = o;
  }
}

// ---------------- global -> LDS direct (16B per lane) ----------------
#define GLOAD(gsrc, ldst)                                                    \
  __builtin_amdgcn_global_load_lds(                                          \
      (const __attribute__((address_space(1))) void*)(gsrc),                 \
      (__attribute__((address_space(3))) void*)(ldst), 16, 0, 0)

// ------ Pass 2: fp4 MFMA GEMM, 256^2 tile, 32x32x64, 2 barriers/tile ------
// LDS per operand: [2 buf][2 khalf][256 rows][64 B] = 64 KB; slot-XOR
// swizzle (slot ^ ((row>>1)&3)) applied on the global source (gload_lds
// writes linearly), undone on ds_read -> conflict-free b128 reads.
// Per K-tile (128 B/row): 2 phases (one per 64 B khalf = 2 ksteps of 64
// fp4), each {stage 4 gloads of next tile's matching khalf; 12 b128 reads;
// 16 MFMA 32x32x64; vmcnt(4); barrier}. In-flight gloads 4<->8, never 0.

#define STG_A(NB, KBo, KH)                                                   \
  GLOAD(aS0 + (KBo) + (KH) * 64, As + (NB) + (KH) * 16384 + dstW);           \
  GLOAD(aS1 + (KBo) + (KH) * 64, As + (NB) + (KH) * 16384 + 8192 + dstW)

#define STG_B(NB, KBo, KH)                                                   \
  GLOAD(bS0 + (KBo) + (KH) * 64, Bs + (NB) + (KH) * 16384 + dstW);           \
  GLOAD(bS1 + (KBo) + (KH) * 64, Bs + (NB) + (KH) * 16384 + 8192 + dstW)

#define VM4BAR                                                               \
  asm volatile("s_waitcnt vmcnt(4)" ::: "memory");                           \
  __builtin_amdgcn_s_barrier();

#define VM0BAR                                                               \
  asm volatile("s_waitcnt vmcnt(0)" ::: "memory");                           \
  __builtin_amdgcn_s_barrier();

#define DO_PHASE(BUFOFF, KHOFF, STAGE_STMT, CLOSE_STMT)                      \
  {                                                                          \
    STAGE_STMT                                                               \
    __builtin_amdgcn_s_setprio(1);                                           \
    _Pragma("unroll")                                                        \
    for (int ks = 0; ks < 2; ++ks) {                                         \
      _Pragma("unroll")                                                      \
      for (int nf = 0; nf < 2; ++nf)                                         \
        *(i32x4*)&bf8[nf] = *(const i32x4*)(Bs + (BUFOFF) + (KHOFF) +        \
                                            bBase + nf * 2048 + kv[ks]);     \
      _Pragma("unroll")                                                      \
      for (int mf = 0; mf < 4; ++mf) {                                       \
        *(i32x4*)&af8[mf & 1] = *(const i32x4*)(As + (BUFOFF) + (KHOFF) +    \
                                                aBase + mf * 2048 + kv[ks]); \
        _Pragma("unroll")                                                    \
        for (int nf = 0; nf < 2; ++nf)                                       \
          acc[mf][nf] = __builtin_amdgcn_mfma_scale_f32_32x32x64_f8f6f4(     \
              af8[mf & 1], bf8[nf], acc[mf][nf], 4, 4, 0, SC1, 0, SC1);      \
      }                                                                      \
    }                                                                        \
    __builtin_amdgcn_s_setprio(0);                                           \
    CLOSE_STMT                                                               \
  }

#define TILE(BUF, NBUF, KBo)                                                 \
  DO_PHASE(BUF, 0,     STG_A(NBUF, KBo, 0); STG_B(NBUF, KBo, 0);, VM4BAR)    \
  DO_PHASE(BUF, 16384, STG_A(NBUF, KBo, 1); STG_B(NBUF, KBo, 1);, VM4BAR)

#define TILE_LAST(BUF)                                                       \
  DO_PHASE(BUF, 0, , VM0BAR)                                                 \
  DO_PHASE(BUF, 16384, , )

__global__ __launch_bounds__(512, 2) void bgemm_fp4_32x32(
    const unsigned char* __restrict__ xa, const unsigned char* __restrict__ wb,
    const float* __restrict__ bias, float* __restrict__ y) {
  __shared__ __align__(16) unsigned char As[65536];
  __shared__ __align__(16) unsigned char Bs[65536];

  const int tid  = threadIdx.x;
  const int lane = tid & 63;
  const int w8   = tid >> 6;   // wave 0..7
  const int wr   = w8 >> 2;    // wave M-row 0..1 (128 rows each)
  const int wc   = w8 & 3;     // wave N-col 0..3 (64 cols each)

  // bijective XCD swizzle (512 blocks, 512 % 8 == 0)
  const int id = blockIdx.x;
  const int sw = ((id & 7) << 6) | (id >> 3);
  const int by = sw >> 4;      // 0..31 M-block
  const int bx = sw & 15;      // 0..15 N-block
  const int m0 = by * BM;
  const int n0 = bx * BN;

  // ---- staging geometry: thread covers LDS row tid>>2, slot tid&3
  const int r0  = tid >> 2;
  const int gsl = (((tid & 3) ^ ((tid >> 3) & 3)) << 4);  // inverse swizzle
  const unsigned char* aS0 = xa + (size_t)(m0 + r0) * KB_ROW + gsl;
  const unsigned char* aS1 = xa + (size_t)(m0 + 128 + r0) * KB_ROW + gsl;
  const unsigned char* bS0 = wb + (size_t)(n0 + r0) * KB_ROW + gsl;
  const unsigned char* bS1 = wb + (size_t)(n0 + 128 + r0) * KB_ROW + gsl;
  const int dstW = w8 * 1024;  // wave-uniform LDS dest (HW adds lane*16)

  // ---- fragment-read geometry (32x32x64 fp4):
  // lane = (row l31) + 32*(16B-half lh); global slot of (ks,lh) = ks*2+lh,
  // stored at LDS slot (ks*2+lh) ^ ((row>>1)&3); row>>1&3 == (l31>>1)&3
  // for all frags (frag strides are multiples of 8 rows).
  const int l31 = lane & 31;
  const int lh  = lane >> 5;
  const int rx  = (l31 >> 1) & 3;
  int kv[2];
  kv[0] = ((0 * 2 + lh) ^ rx) << 4;
  kv[1] = ((1 * 2 + lh) ^ rx) << 4;
  const int aBase = (wr * 128 + l31) * 64;  // + mf*2048 + kv[ks]
  const int bBase = (wc * 64 + l31) * 64;   // + nf*2048 + kv[ks]

  f32x16 acc[4][2];
#pragma unroll
  for (int i = 0; i < 4; ++i)
#pragma unroll
    for (int j = 0; j < 2; ++j)
#pragma unroll
      for (int e = 0; e < 16; ++e) acc[i][j][e] = 0.f;

  // fp4 data lives in the LOW 4 regs of the 8-reg operand; high half stays 0
  i32x8 af8[2], bf8[2];
#pragma unroll
  for (int i = 0; i < 2; ++i) {
    af8[i] = (i32x8){0, 0, 0, 0, 0, 0, 0, 0};
    bf8[i] = (i32x8){0, 0, 0, 0, 0, 0, 0, 0};
  }

  // prologue: stage tile 0 (kh0 then kh1, 8 gloads); wait kh0 batch
  STG_A(0, 0, 0);
  STG_B(0, 0, 0);
  STG_A(0, 0, 1);
  STG_B(0, 0, 1);
  asm volatile("s_waitcnt vmcnt(4)" ::: "memory");
  __builtin_amdgcn_s_barrier();

#pragma unroll 1
  for (int tp = 0; tp < 7; ++tp) {
    const int kb1 = tp * 256 + 128;   // tile 2tp+1
    const int kb2 = tp * 256 + 256;   // tile 2tp+2
    TILE(0, 32768, kb1)
    TILE(32768, 0, kb2)
  }
  TILE(0, 32768, 1920)   // tile 14, stages tile 15
  TILE_LAST(32768)       // tile 15

  // epilogue: 32x32 C/D map: col = lane&31, row = (reg&3)+8*(reg>>2)+4*lh
  float bv[2];
#pragma unroll
  for (int nf = 0; nf < 2; ++nf) bv[nf] = bias[n0 + wc * 64 + nf * 32 + l31];
#pragma unroll
  for (int mf = 0; mf < 4; ++mf) {
#pragma unroll
    for (int j = 0; j < 16; ++j) {
      const int fr = (j & 3) + 8 * (j >> 2) + 4 * lh;
      const int gr = m0 + wr * 128 + mf * 32 + fr;
      float* orow = y + (size_t)gr * N_COLS + n0 + wc * 64 + l31;
#pragma unroll
      for (int nf = 0; nf < 2; ++nf)
        orow[nf * 32] = acc[mf][nf][j] + bv[nf];
    }
  }
}

// =========================================================================
extern "C" void kernel_launch(void* const* d_in, const int* in_sizes, int n_in,
                              void* d_out, int out_size, void* d_ws, size_t ws_size,
                              hipStream_t stream) {
  const float* x    = (const float*)d_in[0];
  const float* wgt  = (const float*)d_in[1];
  const float* bias = (const float*)d_in[2];
  float* y = (float*)d_out;

  unsigned char* xa = (unsigned char*)d_ws;             // 8192*2048 = 16 MB
  unsigned char* wb = xa + (size_t)M_ROWS * KB_ROW;     // 4096*2048 =  8 MB

  binarize_fp4_fused<<<3072, 256, 0, stream>>>(
      (const float4*)x, (const float4*)wgt, (uint4*)xa);

  bgemm_fp4_32x32<<<512, 512, 0, stream>>>(xa, wb, bias, y);
}